// Round 3
// baseline (478.585 us; speedup 1.0000x reference)
//
#include <hip/hip_runtime.h>

// Problem constants: B=1024, T=200, D=128, H=128
#define T_SZ 200
#define H_SZ 128

typedef __attribute__((ext_vector_type(8))) short    bf16x8;
typedef __attribute__((ext_vector_type(4))) float    f32x4;
typedef __attribute__((ext_vector_type(4))) int      i32x4;
typedef __attribute__((ext_vector_type(2))) unsigned u32x2;

__device__ __forceinline__ unsigned short f2bf(float f) {
  unsigned u = __builtin_bit_cast(unsigned, f);
  u += 0x7fffu + ((u >> 16) & 1u);
  return (unsigned short)(u >> 16);
}
__device__ __forceinline__ float bf2f(unsigned us) {
  unsigned v = us << 16;
  return __builtin_bit_cast(float, v);
}
__device__ __forceinline__ float sigmoid_fast(float x) {
  float e = __builtin_amdgcn_exp2f(-1.442695041f * x);
  return __builtin_amdgcn_rcpf(1.0f + e);
}
__device__ __forceinline__ float tanh_fast(float x) {
  float e = __builtin_amdgcn_exp2f(2.885390082f * x);
  return 1.0f - 2.0f * __builtin_amdgcn_rcpf(e + 1.0f);
}
__device__ __forceinline__ f32x4 unpack_bf4(u32x2 p) {
  return (f32x4){ bf2f(p.x & 0xffffu), bf2f(p.x >> 16),
                  bf2f(p.y & 0xffffu), bf2f(p.y >> 16) };
}
// lgkmcnt(0)-only barrier: global loads/stores (vmcnt) stay in flight.
__device__ __forceinline__ void ldsbar() {
  __asm__ __volatile__("" ::: "memory");
  __builtin_amdgcn_s_waitcnt(0xc07f);  // vmcnt(63) expcnt(7) lgkmcnt(0)
  __builtin_amdgcn_s_barrier();
  __asm__ __volatile__("" ::: "memory");
}

// Permuted A-frag layout: element (row m, k-col c) lives at
//   chunk = (c>>5)*64 + ((c>>3)&3)*16 + m,  short-offset = chunk*8 + (c&7).
// Reader lane (m16,q), k-block kb reads 16B at chunk = kb*64 + q*16 + m16
// -> byte addr = 16*lane + kb*1024: perfectly sequential, conflict-free.
__device__ __forceinline__ int frag_elem(int c, int row) {
  return (((c >> 5) * 64 + ((c >> 3) & 3) * 16 + row) << 3) + (c & 7);
}

// ---------------------------------------------------------------------------
// Kernel 1: XGC[bt][t][col(384)][row16] (bf16) = x @ Wx + bias, MFMA C-layout.
// 800 wgs x 16 tiles, depth-2 register prefetch, conflict-free staged frags.
// ---------------------------------------------------------------------------
__global__ __launch_bounds__(256, 3) void xproj_kernel(
    const float* __restrict__ X,   // [B,T,D]
    const float* __restrict__ Wg,  // [256,256]
    const float* __restrict__ bg,  // [256]
    const float* __restrict__ Wc,  // [256,128]
    const float* __restrict__ bc,  // [128]
    unsigned short* __restrict__ XGC)
{
  __shared__ unsigned short Abuf[2][16 * 128];  // permuted frag layout, 4KB each

  const int tid  = threadIdx.x;
  const int lane = tid & 63;
  const int wave = tid >> 6;   // 0..3
  const int m16  = lane & 15;
  const int q    = lane >> 4;

  // Weight B-fragments in registers (one-time).
  bf16x8 wgf[4][4];  // gate cols [64*wave, +64)
  bf16x8 wcf[2][4];  // cand cols [32*wave, +32)
  float  gbias[4], cbias[2];
  #pragma unroll
  for (int nt = 0; nt < 4; ++nt) {
    int col = wave * 64 + nt * 16 + m16;
    gbias[nt] = bg[col];
    #pragma unroll
    for (int kb = 0; kb < 4; ++kb) {
      bf16x8 f;
      #pragma unroll
      for (int j = 0; j < 8; ++j)
        f[j] = (short)f2bf(Wg[(size_t)(kb * 32 + q * 8 + j) * 256 + col]);
      wgf[nt][kb] = f;
    }
  }
  #pragma unroll
  for (int nt = 0; nt < 2; ++nt) {
    int col = wave * 32 + nt * 16 + m16;
    cbias[nt] = bc[col];
    #pragma unroll
    for (int kb = 0; kb < 4; ++kb) {
      bf16x8 f;
      #pragma unroll
      for (int j = 0; j < 8; ++j)
        f[j] = (short)f2bf(Wc[(size_t)(kb * 32 + q * 8 + j) * 128 + col]);
      wcf[nt][kb] = f;
    }
  }

  const int srow  = tid >> 4;        // 0..15 staging row (coalesced X reads)
  const int scol  = (tid & 15) * 8;  // 8 consecutive k per thread = one chunk
  const int schunk = (tid & 15) * 16 + srow;  // frag-layout chunk id
  const int t0   = blockIdx.x * 16;  // 800 wgs x 16 tiles = 12800

  auto gload = [&](int tile, f32x4& a, f32x4& b) {
    int bt = tile / 200, t = tile % 200;
    const float* p = X + ((size_t)(bt * 16 + srow) * T_SZ + t) * 128 + scol;
    a = *(const f32x4*)p;
    b = *(const f32x4*)(p + 4);
  };

  auto compute = [&](int tile, const f32x4& pa, const f32x4& pb, int parity) {
    unsigned short* buf = Abuf[parity];
    // stage (one ds_write_b128/thread into permuted layout)
    unsigned d0 = f2bf(pa.x) | ((unsigned)f2bf(pa.y) << 16);
    unsigned d1 = f2bf(pa.z) | ((unsigned)f2bf(pa.w) << 16);
    unsigned d2 = f2bf(pb.x) | ((unsigned)f2bf(pb.y) << 16);
    unsigned d3 = f2bf(pb.z) | ((unsigned)f2bf(pb.w) << 16);
    i32x4 pk = { (int)d0, (int)d1, (int)d2, (int)d3 };
    *(i32x4*)&buf[schunk * 8] = pk;
    ldsbar();
    bf16x8 af[4];
    #pragma unroll
    for (int kb = 0; kb < 4; ++kb)
      af[kb] = __builtin_bit_cast(bf16x8, *(const i32x4*)&buf[(kb * 64 + q * 16 + m16) * 8]);
    int bt = tile / 200, t = tile % 200;
    unsigned short* outbase = XGC + ((size_t)bt * 200 + t) * 384 * 16;
    #pragma unroll
    for (int nt = 0; nt < 4; ++nt) {
      f32x4 acc = { gbias[nt], gbias[nt], gbias[nt], gbias[nt] };
      #pragma unroll
      for (int kb = 0; kb < 4; ++kb)
        acc = __builtin_amdgcn_mfma_f32_16x16x32_bf16(af[kb], wgf[nt][kb], acc, 0, 0, 0);
      int col = wave * 64 + nt * 16 + m16;
      unsigned h0 = f2bf(acc[0]), h1 = f2bf(acc[1]), h2 = f2bf(acc[2]), h3 = f2bf(acc[3]);
      u32x2 pko = { h0 | (h1 << 16), h2 | (h3 << 16) };
      *(u32x2*)(outbase + col * 16 + q * 4) = pko;
    }
    #pragma unroll
    for (int nt = 0; nt < 2; ++nt) {
      f32x4 acc = { cbias[nt], cbias[nt], cbias[nt], cbias[nt] };
      #pragma unroll
      for (int kb = 0; kb < 4; ++kb)
        acc = __builtin_amdgcn_mfma_f32_16x16x32_bf16(af[kb], wcf[nt][kb], acc, 0, 0, 0);
      int col = 256 + wave * 32 + nt * 16 + m16;
      unsigned h0 = f2bf(acc[0]), h1 = f2bf(acc[1]), h2 = f2bf(acc[2]), h3 = f2bf(acc[3]);
      u32x2 pko = { h0 | (h1 << 16), h2 | (h3 << 16) };
      *(u32x2*)(outbase + col * 16 + q * 4) = pko;
    }
  };

  f32x4 pa0, pb0, pa1, pb1;
  gload(t0, pa0, pb0);
  gload(t0 + 1, pa1, pb1);

  for (int it = 0; it < 16; it += 2) {
    f32x4 ca = pa0, cb = pb0;
    // compute consumes (ca,cb); prefetch depth stays 2
    {
      unsigned short* buf = Abuf[0];
      unsigned d0 = f2bf(ca.x) | ((unsigned)f2bf(ca.y) << 16);
      unsigned d1 = f2bf(ca.z) | ((unsigned)f2bf(ca.w) << 16);
      unsigned d2 = f2bf(cb.x) | ((unsigned)f2bf(cb.y) << 16);
      unsigned d3 = f2bf(cb.z) | ((unsigned)f2bf(cb.w) << 16);
      i32x4 pk = { (int)d0, (int)d1, (int)d2, (int)d3 };
      *(i32x4*)&buf[schunk * 8] = pk;
    }
    ldsbar();
    if (it + 2 < 16) gload(t0 + it + 2, pa0, pb0);
    compute_body0:
    {
      unsigned short* buf = Abuf[0];
      bf16x8 af[4];
      #pragma unroll
      for (int kb = 0; kb < 4; ++kb)
        af[kb] = __builtin_bit_cast(bf16x8, *(const i32x4*)&buf[(kb * 64 + q * 16 + m16) * 8]);
      int tile = t0 + it;
      int bt = tile / 200, t = tile % 200;
      unsigned short* outbase = XGC + ((size_t)bt * 200 + t) * 384 * 16;
      #pragma unroll
      for (int nt = 0; nt < 4; ++nt) {
        f32x4 acc = { gbias[nt], gbias[nt], gbias[nt], gbias[nt] };
        #pragma unroll
        for (int kb = 0; kb < 4; ++kb)
          acc = __builtin_amdgcn_mfma_f32_16x16x32_bf16(af[kb], wgf[nt][kb], acc, 0, 0, 0);
        int col = wave * 64 + nt * 16 + m16;
        unsigned h0 = f2bf(acc[0]), h1 = f2bf(acc[1]), h2 = f2bf(acc[2]), h3 = f2bf(acc[3]);
        u32x2 pko = { h0 | (h1 << 16), h2 | (h3 << 16) };
        *(u32x2*)(outbase + col * 16 + q * 4) = pko;
      }
      #pragma unroll
      for (int nt = 0; nt < 2; ++nt) {
        f32x4 acc = { cbias[nt], cbias[nt], cbias[nt], cbias[nt] };
        #pragma unroll
        for (int kb = 0; kb < 4; ++kb)
          acc = __builtin_amdgcn_mfma_f32_16x16x32_bf16(af[kb], wcf[nt][kb], acc, 0, 0, 0);
        int col = 256 + wave * 32 + nt * 16 + m16;
        unsigned h0 = f2bf(acc[0]), h1 = f2bf(acc[1]), h2 = f2bf(acc[2]), h3 = f2bf(acc[3]);
        u32x2 pko = { h0 | (h1 << 16), h2 | (h3 << 16) };
        *(u32x2*)(outbase + col * 16 + q * 4) = pko;
      }
    }
    // odd tile
    {
      unsigned short* buf = Abuf[1];
      unsigned d0 = f2bf(pa1.x) | ((unsigned)f2bf(pa1.y) << 16);
      unsigned d1 = f2bf(pa1.z) | ((unsigned)f2bf(pa1.w) << 16);
      unsigned d2 = f2bf(pb1.x) | ((unsigned)f2bf(pb1.y) << 16);
      unsigned d3 = f2bf(pb1.z) | ((unsigned)f2bf(pb1.w) << 16);
      i32x4 pk = { (int)d0, (int)d1, (int)d2, (int)d3 };
      *(i32x4*)&buf[schunk * 8] = pk;
    }
    ldsbar();
    if (it + 3 < 16) gload(t0 + it + 3, pa1, pb1);
    {
      unsigned short* buf = Abuf[1];
      bf16x8 af[4];
      #pragma unroll
      for (int kb = 0; kb < 4; ++kb)
        af[kb] = __builtin_bit_cast(bf16x8, *(const i32x4*)&buf[(kb * 64 + q * 16 + m16) * 8]);
      int tile = t0 + it + 1;
      int bt = tile / 200, t = tile % 200;
      unsigned short* outbase = XGC + ((size_t)bt * 200 + t) * 384 * 16;
      #pragma unroll
      for (int nt = 0; nt < 4; ++nt) {
        f32x4 acc = { gbias[nt], gbias[nt], gbias[nt], gbias[nt] };
        #pragma unroll
        for (int kb = 0; kb < 4; ++kb)
          acc = __builtin_amdgcn_mfma_f32_16x16x32_bf16(af[kb], wgf[nt][kb], acc, 0, 0, 0);
        int col = wave * 64 + nt * 16 + m16;
        unsigned h0 = f2bf(acc[0]), h1 = f2bf(acc[1]), h2 = f2bf(acc[2]), h3 = f2bf(acc[3]);
        u32x2 pko = { h0 | (h1 << 16), h2 | (h3 << 16) };
        *(u32x2*)(outbase + col * 16 + q * 4) = pko;
      }
      #pragma unroll
      for (int nt = 0; nt < 2; ++nt) {
        f32x4 acc = { cbias[nt], cbias[nt], cbias[nt], cbias[nt] };
        #pragma unroll
        for (int kb = 0; kb < 4; ++kb)
          acc = __builtin_amdgcn_mfma_f32_16x16x32_bf16(af[kb], wcf[nt][kb], acc, 0, 0, 0);
        int col = 256 + wave * 32 + nt * 16 + m16;
        unsigned h0 = f2bf(acc[0]), h1 = f2bf(acc[1]), h2 = f2bf(acc[2]), h3 = f2bf(acc[3]);
        u32x2 pko = { h0 | (h1 << 16), h2 | (h3 << 16) };
        *(u32x2*)(outbase + col * 16 + q * 4) = pko;
      }
    }
  }
  (void)0;
}

// ---------------------------------------------------------------------------
// Kernel 2: GRU recurrence. 64 wgs x 512 threads (8 waves).
// P1 (all waves): gates = sigmoid(XG + h@Whg); r-waves write rh (bf16, frag
//   layout); u-waves keep u in registers.
// P2 (u-waves only): c = tanh(XC + rh@Whc); h update for their own 32 cols.
// No ubuf, no fp32 h copy; 2 lgkm barriers/step; named prefetch registers.
// ---------------------------------------------------------------------------
__global__ __launch_bounds__(512, 1) void gru_kernel(
    const unsigned short* __restrict__ XGC,
    const int*   __restrict__ seq_len,
    const float* __restrict__ Wg,   // [256,256] rows 128.. = h-part
    const float* __restrict__ Wc,   // [256,128] rows 128.. = h-part
    float* __restrict__ Y)          // [B,T,H]
{
  __shared__ unsigned short hA[16 * 128];   // h bf16, permuted frag layout
  __shared__ unsigned short rhA[16 * 128];  // r*h bf16, permuted frag layout

  const int tid  = threadIdx.x;
  const int lane = tid & 63;
  const int w    = tid >> 6;   // 0..7
  const int m16  = lane & 15;
  const int q    = lane >> 4;
  const bool is_u = (w >= 4);

  // Gate weights: wave w owns gate cols [32w, 32w+32) (2 x 16-col tiles).
  bf16x8 wgf[2][4];
  #pragma unroll
  for (int nt = 0; nt < 2; ++nt)
    #pragma unroll
    for (int kb = 0; kb < 4; ++kb) {
      bf16x8 f;
      #pragma unroll
      for (int j = 0; j < 8; ++j)
        f[j] = (short)f2bf(Wg[(size_t)(128 + kb * 32 + q * 8 + j) * 256 + w * 32 + nt * 16 + m16]);
      wgf[nt][kb] = f;
    }
  // Cand weights: u-wave w owns cand cols [32(w-4), +32).
  bf16x8 wcf[2][4];
  if (is_u) {
    #pragma unroll
    for (int nt = 0; nt < 2; ++nt)
      #pragma unroll
      for (int kb = 0; kb < 4; ++kb) {
        bf16x8 f;
        #pragma unroll
        for (int j = 0; j < 8; ++j)
          f[j] = (short)f2bf(Wc[(size_t)(128 + kb * 32 + q * 8 + j) * 128 + (w - 4) * 32 + nt * 16 + m16]);
        wcf[nt][kb] = f;
      }
  }

  const int bt = blockIdx.x;  // 0..63
  int slen[4];
  #pragma unroll
  for (int i = 0; i < 4; ++i) slen[i] = seq_len[bt * 16 + q * 4 + i];

  float h0_ = 0.f, h1_ = 0.f, h2_ = 0.f, h3_ = 0.f;   // col block nt=0, rows q*4+i
  float h4_ = 0.f, h5_ = 0.f, h6_ = 0.f, h7_ = 0.f;   // col block nt=1

  // Per-thread LDS element offsets for cols c(nt) = 32*(w&3) + nt*16 + m16
  int cA = 32 * (w & 3) + m16;
  int cB = cA + 16;
  int eA = frag_elem(cA, q * 4);  // +8 per row
  int eB = frag_elem(cB, q * 4);

  for (int idx = tid; idx < 16 * 128; idx += 512) hA[idx] = 0;

  const unsigned short* xg = XGC + (size_t)bt * 200 * 384 * 16;
  const int goffA = (w * 32 + m16) * 16 + q * 4;
  const int goffB = (w * 32 + 16 + m16) * 16 + q * 4;
  const int coffA = (256 + (w - 4) * 32 + m16) * 16 + q * 4;
  const int coffB = (256 + (w - 4) * 32 + 16 + m16) * 16 + q * 4;

#define LOADG(t, GA, GB) do { \
    const unsigned short* _b = xg + (size_t)(t) * 6144; \
    GA = *(const u32x2*)(_b + goffA); \
    GB = *(const u32x2*)(_b + goffB); } while (0)
#define LOADC(t, CA, CB) do { \
    const unsigned short* _b = xg + (size_t)(t) * 6144; \
    CA = *(const u32x2*)(_b + coffA); \
    CB = *(const u32x2*)(_b + coffB); } while (0)

  u32x2 g0a, g0b, c0a, c0b, g1a, g1b, c1a, c1b;
  LOADG(0, g0a, g0b);
  LOADG(1, g1a, g1b);
  if (is_u) { LOADC(0, c0a, c0b); LOADC(1, c1a, c1b); }
  ldsbar();  // hA zero-init visible

#define STEP(T, GA, GB, CA, CB) do { \
    /* ---- P1: gates ---- */ \
    bf16x8 af0 = __builtin_bit_cast(bf16x8, *(const i32x4*)&hA[(0 * 64 + q * 16 + m16) * 8]); \
    bf16x8 af1 = __builtin_bit_cast(bf16x8, *(const i32x4*)&hA[(1 * 64 + q * 16 + m16) * 8]); \
    bf16x8 af2 = __builtin_bit_cast(bf16x8, *(const i32x4*)&hA[(2 * 64 + q * 16 + m16) * 8]); \
    bf16x8 af3 = __builtin_bit_cast(bf16x8, *(const i32x4*)&hA[(3 * 64 + q * 16 + m16) * 8]); \
    float hsA[4], hsB[4]; \
    if (!is_u) { \
      _Pragma("unroll") for (int i = 0; i < 4; ++i) { \
        hsA[i] = bf2f(hA[eA + i * 8]); hsB[i] = bf2f(hA[eB + i * 8]); } \
    } \
    f32x4 accA = unpack_bf4(GA), accB = unpack_bf4(GB); \
    f32x4 ccA, ccB; \
    if (is_u) { ccA = unpack_bf4(CA); ccB = unpack_bf4(CB); } \
    if ((T) < 198) { LOADG((T) + 2, GA, GB); if (is_u) LOADC((T) + 2, CA, CB); } \
    accA = __builtin_amdgcn_mfma_f32_16x16x32_bf16(af0, wgf[0][0], accA, 0, 0, 0); \
    accB = __builtin_amdgcn_mfma_f32_16x16x32_bf16(af0, wgf[1][0], accB, 0, 0, 0); \
    accA = __builtin_amdgcn_mfma_f32_16x16x32_bf16(af1, wgf[0][1], accA, 0, 0, 0); \
    accB = __builtin_amdgcn_mfma_f32_16x16x32_bf16(af1, wgf[1][1], accB, 0, 0, 0); \
    accA = __builtin_amdgcn_mfma_f32_16x16x32_bf16(af2, wgf[0][2], accA, 0, 0, 0); \
    accB = __builtin_amdgcn_mfma_f32_16x16x32_bf16(af2, wgf[1][2], accB, 0, 0, 0); \
    accA = __builtin_amdgcn_mfma_f32_16x16x32_bf16(af3, wgf[0][3], accA, 0, 0, 0); \
    accB = __builtin_amdgcn_mfma_f32_16x16x32_bf16(af3, wgf[1][3], accB, 0, 0, 0); \
    float gA0 = sigmoid_fast(accA[0]), gA1 = sigmoid_fast(accA[1]); \
    float gA2 = sigmoid_fast(accA[2]), gA3 = sigmoid_fast(accA[3]); \
    float gB0 = sigmoid_fast(accB[0]), gB1 = sigmoid_fast(accB[1]); \
    float gB2 = sigmoid_fast(accB[2]), gB3 = sigmoid_fast(accB[3]); \
    if (!is_u) {  /* r-waves: rh -> rhA */ \
      rhA[eA + 0] = f2bf(gA0 * hsA[0]); rhA[eA + 8]  = f2bf(gA1 * hsA[1]); \
      rhA[eA + 16] = f2bf(gA2 * hsA[2]); rhA[eA + 24] = f2bf(gA3 * hsA[3]); \
      rhA[eB + 0] = f2bf(gB0 * hsB[0]); rhA[eB + 8]  = f2bf(gB1 * hsB[1]); \
      rhA[eB + 16] = f2bf(gB2 * hsB[2]); rhA[eB + 24] = f2bf(gB3 * hsB[3]); \
    } \
    ldsbar(); \
    /* ---- P2: candidate + h update (u-waves only) ---- */ \
    if (is_u) { \
      bf16x8 rf0 = __builtin_bit_cast(bf16x8, *(const i32x4*)&rhA[(0 * 64 + q * 16 + m16) * 8]); \
      bf16x8 rf1 = __builtin_bit_cast(bf16x8, *(const i32x4*)&rhA[(1 * 64 + q * 16 + m16) * 8]); \
      bf16x8 rf2 = __builtin_bit_cast(bf16x8, *(const i32x4*)&rhA[(2 * 64 + q * 16 + m16) * 8]); \
      bf16x8 rf3 = __builtin_bit_cast(bf16x8, *(const i32x4*)&rhA[(3 * 64 + q * 16 + m16) * 8]); \
      ccA = __builtin_amdgcn_mfma_f32_16x16x32_bf16(rf0, wcf[0][0], ccA, 0, 0, 0); \
      ccB = __builtin_amdgcn_mfma_f32_16x16x32_bf16(rf0, wcf[1][0], ccB, 0, 0, 0); \
      ccA = __builtin_amdgcn_mfma_f32_16x16x32_bf16(rf1, wcf[0][1], ccA, 0, 0, 0); \
      ccB = __builtin_amdgcn_mfma_f32_16x16x32_bf16(rf1, wcf[1][1], ccB, 0, 0, 0); \
      ccA = __builtin_amdgcn_mfma_f32_16x16x32_bf16(rf2, wcf[0][2], ccA, 0, 0, 0); \
      ccB = __builtin_amdgcn_mfma_f32_16x16x32_bf16(rf2, wcf[1][2], ccB, 0, 0, 0); \
      ccA = __builtin_amdgcn_mfma_f32_16x16x32_bf16(rf3, wcf[0][3], ccA, 0, 0, 0); \
      ccB = __builtin_amdgcn_mfma_f32_16x16x32_bf16(rf3, wcf[1][3], ccB, 0, 0, 0); \
      float* _Y = Y + ((size_t)(bt * 16 + q * 4) * T_SZ + (T)) * H_SZ + (w - 4) * 32 + m16; \
      const size_t _ys = (size_t)T_SZ * H_SZ; \
      float c0 = tanh_fast(ccA[0]), c1 = tanh_fast(ccA[1]); \
      float c2 = tanh_fast(ccA[2]), c3 = tanh_fast(ccA[3]); \
      float c4 = tanh_fast(ccB[0]), c5 = tanh_fast(ccB[1]); \
      float c6 = tanh_fast(ccB[2]), c7 = tanh_fast(ccB[3]); \
      float n0 = gA0 * (h0_ - c0) + c0, n1 = gA1 * (h1_ - c1) + c1; \
      float n2 = gA2 * (h2_ - c2) + c2, n3 = gA3 * (h3_ - c3) + c3; \
      float n4 = gB0 * (h4_ - c4) + c4, n5 = gB1 * (h5_ - c5) + c5; \
      float n6 = gB2 * (h6_ - c6) + c6, n7 = gB3 * (h7_ - c7) + c7; \
      bool v0 = (T) < slen[0], v1 = (T) < slen[1], v2 = (T) < slen[2], v3 = (T) < slen[3]; \
      h0_ = v0 ? n0 : h0_; h1_ = v1 ? n1 : h1_; h2_ = v2 ? n2 : h2_; h3_ = v3 ? n3 : h3_; \
      h4_ = v0 ? n4 : h4_; h5_ = v1 ? n5 : h5_; h6_ = v2 ? n6 : h6_; h7_ = v3 ? n7 : h7_; \
      _Y[0]          = v0 ? n0 : 0.f; _Y[_ys]         = v1 ? n1 : 0.f; \
      _Y[2 * _ys]    = v2 ? n2 : 0.f; _Y[3 * _ys]     = v3 ? n3 : 0.f; \
      _Y[16]         = v0 ? n4 : 0.f; _Y[_ys + 16]    = v1 ? n5 : 0.f; \
      _Y[2 * _ys + 16] = v2 ? n6 : 0.f; _Y[3 * _ys + 16] = v3 ? n7 : 0.f; \
      hA[eA + 0] = f2bf(h0_); hA[eA + 8]  = f2bf(h1_); \
      hA[eA + 16] = f2bf(h2_); hA[eA + 24] = f2bf(h3_); \
      hA[eB + 0] = f2bf(h4_); hA[eB + 8]  = f2bf(h5_); \
      hA[eB + 16] = f2bf(h6_); hA[eB + 24] = f2bf(h7_); \
    } \
    ldsbar(); \
  } while (0)

  for (int t = 0; t < 200; t += 2) {
    STEP(t,     g0a, g0b, c0a, c0b);
    STEP(t + 1, g1a, g1b, c1a, c1b);
  }
#undef STEP
#undef LOADG
#undef LOADC
}

extern "C" void kernel_launch(void* const* d_in, const int* in_sizes, int n_in,
                              void* d_out, int out_size, void* d_ws, size_t ws_size,
                              hipStream_t stream) {
  const float* X   = (const float*)d_in[0];
  const int*   seq = (const int*)  d_in[1];
  const float* Wg  = (const float*)d_in[2];
  const float* bg  = (const float*)d_in[3];
  const float* Wc  = (const float*)d_in[4];
  const float* bc  = (const float*)d_in[5];
  float* Y = (float*)d_out;
  unsigned short* XGC = (unsigned short*)d_ws;  // 64*200*384*16 bf16 = 157 MB

  hipLaunchKernelGGL(xproj_kernel, dim3(800), dim3(256), 0, stream, X, Wg, bg, Wc, bc, XGC);
  hipLaunchKernelGGL(gru_kernel,   dim3(64),  dim3(512), 0, stream, XGC, seq, Wg, Wc, Y);
}